// Round 1
// baseline (870.936 us; speedup 1.0000x reference)
//
#include <hip/hip_runtime.h>

#define NPTS 8192
#define DIM 128
#define NCLS 128
#define KSEL 17      // k+1 smallest define the threshold
#define CAP 64       // per-(wave,row) candidate buffer capacity
#define CT 48        // compact when cnt > CT (<=16 appends/iter/row keeps cnt <= CAP)
#define BIG 3.0e38f

typedef short bf16x8 __attribute__((ext_vector_type(8)));
typedef float f32x4 __attribute__((ext_vector_type(4)));

__device__ __forceinline__ unsigned short f2bf(float f) {
  unsigned int u = __float_as_uint(f);
  u += 0x7fffu + ((u >> 16) & 1u);   // round-to-nearest-even
  return (unsigned short)(u >> 16);
}

// ---- per-class stats: count, first index (j0), second index (j1); also int32 targets
__global__ void prep_t(const long long* __restrict__ targets, int* __restrict__ tgt,
                       int* __restrict__ ccount, int* __restrict__ j0a, int* __restrict__ j1a) {
  __shared__ int cc[NCLS], c0[NCLS], c1[NCLS];
  int tid = threadIdx.x;
  if (tid < NCLS) { cc[tid] = 0; c0[tid] = 0x7fffffff; c1[tid] = 0x7fffffff; }
  __syncthreads();
  for (int j = tid; j < NPTS; j += 256) {
    int c = (int)targets[j];
    tgt[j] = c;
    atomicAdd(&cc[c], 1);
    atomicMin(&c0[c], j);
  }
  __syncthreads();
  for (int j = tid; j < NPTS; j += 256) {
    int c = (int)targets[j];
    if (j != c0[c]) atomicMin(&c1[c], j);
  }
  __syncthreads();
  if (tid < NCLS) { ccount[tid] = cc[tid]; j0a[tid] = c0[tid]; j1a[tid] = c1[tid]; }
}

// ---- bf16 copy of X + exact fp32 squared norms (one wave per row)
__global__ void prep_x(const float* __restrict__ X, unsigned short* __restrict__ Xb,
                       float* __restrict__ sqv) {
  int gw = (int)((blockIdx.x * blockDim.x + threadIdx.x) >> 6);
  int lane = threadIdx.x & 63;
  if (gw >= NPTS) return;
  const float* xr = X + (size_t)gw * DIM;
  float a = xr[lane], b = xr[lane + 64];
  Xb[(size_t)gw * DIM + lane] = f2bf(a);
  Xb[(size_t)gw * DIM + lane + 64] = f2bf(b);
  float s = a * a + b * b;
#pragma unroll
  for (int off = 32; off; off >>= 1) s += __shfl_xor(s, off);
  if (lane == 0) sqv[gw] = s;
}

// ---- fused distance GEMM + exact streaming top-17 + loss epilogue
// Block: 256 threads = 4 waves; block owns 16 rows; wave w scans column slab [w*2048, (w+1)*2048).
__global__ __launch_bounds__(256) void knn_main(
    const unsigned short* __restrict__ Xb, const float* __restrict__ sqv,
    const int* __restrict__ tgt, const int* __restrict__ ccount,
    const int* __restrict__ j0a, const int* __restrict__ j1a,
    const float* __restrict__ X32, float* __restrict__ out) {
  __shared__ float bufD[4][16][CAP];
  __shared__ int   bufM[4][16][CAP];
  __shared__ int   cnt[4][16];
  __shared__ float cutv[4][16];
  __shared__ float blockAcc[4];

  const int tid = threadIdx.x;
  const int w = tid >> 6;
  const int lane = tid & 63;
  const int quad = lane >> 4;
  const int l16 = lane & 15;
  const int rbase = blockIdx.x * 16;

  if (tid < 4) blockAcc[tid] = 0.0f;
  if (lane < 16) { cnt[w][lane] = 0; cutv[w][lane] = BIG; }
  __syncthreads();

  // A fragments (16 rows x K=128), persistent in 16 VGPRs.
  // 16x16x32 bf16 layout: A[m=lane&15][k=quad*8+j]  (verified m89/m91)
  bf16x8 afrag[4];
  {
    const unsigned short* arow = Xb + (size_t)(rbase + l16) * DIM;
#pragma unroll
    for (int kb = 0; kb < 4; kb++)
      afrag[kb] = *(const bf16x8*)(arow + kb * 32 + quad * 8);
  }
  // per-lane cached row stats (this lane's 4 C-rows: quad*4+r)
  float sqi[4]; int ti[4];
#pragma unroll
  for (int r = 0; r < 4; r++) { int rr = rbase + quad * 4 + r; sqi[r] = sqv[rr]; ti[r] = tgt[rr]; }

  for (int t = 0; t < 128; t++) {
    const int col = w * 2048 + t * 16 + l16;
    const unsigned short* brow = Xb + (size_t)col * DIM;
    bf16x8 bfrag[4];
#pragma unroll
    for (int kb = 0; kb < 4; kb++) bfrag[kb] = *(const bf16x8*)(brow + kb * 32 + quad * 8);
    f32x4 acc = {0.f, 0.f, 0.f, 0.f};
#pragma unroll
    for (int kb = 0; kb < 4; kb++)
      acc = __builtin_amdgcn_mfma_f32_16x16x32_bf16(afrag[kb], bfrag[kb], acc, 0, 0, 0);

    const float sqj = sqv[col];
    const int tj = tgt[col];
#pragma unroll
    for (int r = 0; r < 4; r++) {
      const int rl = quad * 4 + r;                 // C/D: col=lane&15, row=quad*4+reg
      const float d2 = sqi[r] + sqj - 2.0f * acc[r];
      if ((col != rbase + rl) && (d2 < cutv[w][rl])) {
        int pos = atomicAdd(&cnt[w][rl], 1);
        if (pos < CAP) { bufD[w][rl][pos] = d2; bufM[w][rl][pos] = (tj == ti[r]); }
      }
    }
    // compaction: keep 17 smallest, tighten cutoff to the 17th value (exact)
    int need = (lane < 16) ? (cnt[w][lane] > CT) : 0;
    unsigned long long mask = __ballot(need);
    while (mask) {
      const int rl = __ffsll(mask) - 1; mask &= (mask - 1);
      const int n = min(cnt[w][rl], CAP);
      float e = (lane < n) ? bufD[w][rl][lane] : BIG;
      int  em = (lane < n) ? bufM[w][rl][lane] : 0;
      float last = BIG;
      for (int round = 0; round < KSEL; round++) {
        float v = e; int idx = lane;
#pragma unroll
        for (int off = 32; off; off >>= 1) {
          float ov = __shfl_xor(v, off);
          int   oi = __shfl_xor(idx, off);
          if (ov < v || (ov == v && oi < idx)) { v = ov; idx = oi; }
        }
        if (lane == idx) { bufD[w][rl][round] = e; bufM[w][rl][round] = em; e = BIG; }
        last = v;
      }
      if (lane == 0) { cnt[w][rl] = KSEL; cutv[w][rl] = last; }
    }
  }
  __syncthreads();

  // finalize: wave w handles local rows w*4 .. w*4+3; merge the 4 wave-streams
  for (int ri = 0; ri < 4; ri++) {
    const int rl = w * 4 + ri;
    const int grow = rbase + rl;
    float e[4]; int m[4];
#pragma unroll
    for (int ww = 0; ww < 4; ww++) {
      const int n = min(cnt[ww][rl], CAP);
      if (lane < n) { e[ww] = bufD[ww][rl][lane]; m[ww] = bufM[ww][rl][lane]; }
      else { e[ww] = BIG; m[ww] = 0; }
    }
    // 17 extraction rounds over the <=256 candidates -> 17th-smallest d2
    float w0 = e[0], w1 = e[1], w2 = e[2], w3 = e[3];
    float v17 = BIG;
    for (int round = 0; round < KSEL; round++) {
      float v = w0; int idx = lane;
      if (w1 < v) { v = w1; idx = lane | (1 << 6); }
      if (w2 < v) { v = w2; idx = lane | (2 << 6); }
      if (w3 < v) { v = w3; idx = lane | (3 << 6); }
#pragma unroll
      for (int off = 32; off; off >>= 1) {
        float ov = __shfl_xor(v, off);
        int   oi = __shfl_xor(idx, off);
        if (ov < v || (ov == v && oi < idx)) { v = ov; idx = oi; }
      }
      if ((idx & 63) == lane) {
        int s = idx >> 6;
        if (s == 0) w0 = BIG; else if (s == 1) w1 = BIG; else if (s == 2) w2 = BIG; else w3 = BIG;
      }
      v17 = v;
    }
    const float thr = sqrtf(fmaxf(v17, 1e-12f));   // reference: strict dist < thr
    float pls = 0.f, nls = 0.f; int cp = 0, cn = 0;
#pragma unroll
    for (int s = 0; s < 4; s++) {
      if (e[s] < BIG) {
        float dist = sqrtf(fmaxf(e[s], 1e-12f));
        if (dist < thr) {
          float ex = expf(-dist);
          if (m[s]) { pls += ex; cp++; } else { nls += ex; cn++; }
        }
      }
    }
#pragma unroll
    for (int off = 32; off; off >>= 1) {
      pls += __shfl_xor(pls, off);
      nls += __shfl_xor(nls, off);
      cp  += __shfl_xor(cp, off);
      cn  += __shfl_xor(cn, off);
    }
    const int c = tgt[grow];
    const int ncl = ccount[c];
    const bool valid = (ncl > 1) && (ncl < NPTS);
    if (valid) {
      float pos_eff;
      if (cp == 0) {
        // fallback: first positive by index order, exact fp32 distance
        const int jf = (grow == j0a[c]) ? j1a[c] : j0a[c];
        const float* xi = X32 + (size_t)grow * DIM;
        const float* xj = X32 + (size_t)jf * DIM;
        float p = xi[lane] * xj[lane] + xi[lane + 64] * xj[lane + 64];
#pragma unroll
        for (int off = 32; off; off >>= 1) p += __shfl_xor(p, off);
        const float fb2 = sqv[grow] + sqv[jf] - 2.0f * p;
        pos_eff = expf(-sqrtf(fmaxf(fb2, 1e-12f)));
      } else {
        pos_eff = pls;
      }
      if (lane == 0) {
        const float loss_i = -logf(pos_eff / (pos_eff + nls));
        const int cpa = (cp == 0) ? 1 : cp;
        atomicAdd(&blockAcc[0], loss_i);
        atomicAdd(&blockAcc[1], (cpa > cn) ? 1.0f : 0.0f);
        atomicAdd(&blockAcc[2], (float)cp);
        atomicAdd(&blockAcc[3], (float)cn);
      }
    }
  }
  __syncthreads();
  if (tid < 4) atomicAdd(&out[tid], blockAcc[tid] * (1.0f / (float)NPTS));
}

extern "C" void kernel_launch(void* const* d_in, const int* in_sizes, int n_in,
                              void* d_out, int out_size, void* d_ws, size_t ws_size,
                              hipStream_t stream) {
  const float* X = (const float*)d_in[0];
  const long long* targets = (const long long*)d_in[1];
  float* out = (float*)d_out;

  char* ws = (char*)d_ws;
  unsigned short* Xb = (unsigned short*)ws;                      // 8192*128*2 = 2 MiB
  float* sqv  = (float*)(ws + 2u * 1024u * 1024u);               // 32 KiB
  int*   tgt  = (int*)  (ws + 2u * 1024u * 1024u + 32u * 1024u); // 32 KiB
  int* ccount = (int*)  (ws + 2u * 1024u * 1024u + 64u * 1024u); // 512 B
  int* j0a = ccount + NCLS;
  int* j1a = j0a + NCLS;

  hipMemsetAsync(d_out, 0, 4 * sizeof(float), stream);
  prep_t<<<1, 256, 0, stream>>>(targets, tgt, ccount, j0a, j1a);
  prep_x<<<2048, 256, 0, stream>>>(X, Xb, sqv);
  knn_main<<<512, 256, 0, stream>>>(Xb, sqv, tgt, ccount, j0a, j1a, X, out);
}

// Round 2
// 416.239 us; speedup vs baseline: 2.0924x; 2.0924x over previous
//
#include <hip/hip_runtime.h>

#define NPTS 8192
#define DIM 128
#define NCLS 128
#define KSEL 17      // k+1 smallest define the threshold
#define CAPW 40      // per-(wave,row) sweep-2 candidate capacity (expected ~5 used)
#define BIG 3.0e38f

typedef short bf16x8 __attribute__((ext_vector_type(8)));
typedef float f32x4 __attribute__((ext_vector_type(4)));

__device__ __forceinline__ unsigned short f2bf(float f) {
  unsigned int u = __float_as_uint(f);
  u += 0x7fffu + ((u >> 16) & 1u);   // round-to-nearest-even
  return (unsigned short)(u >> 16);
}

// ---- per-class stats: count, first index (j0), second index (j1); also int32 targets
__global__ void prep_t(const long long* __restrict__ targets, int* __restrict__ tgt,
                       int* __restrict__ ccount, int* __restrict__ j0a, int* __restrict__ j1a) {
  __shared__ int cc[NCLS], c0[NCLS], c1[NCLS];
  int tid = threadIdx.x;
  if (tid < NCLS) { cc[tid] = 0; c0[tid] = 0x7fffffff; c1[tid] = 0x7fffffff; }
  __syncthreads();
  for (int j = tid; j < NPTS; j += 256) {
    int c = (int)targets[j];
    tgt[j] = c;
    atomicAdd(&cc[c], 1);
    atomicMin(&c0[c], j);
  }
  __syncthreads();
  for (int j = tid; j < NPTS; j += 256) {
    int c = (int)targets[j];
    if (j != c0[c]) atomicMin(&c1[c], j);
  }
  __syncthreads();
  if (tid < NCLS) { ccount[tid] = cc[tid]; j0a[tid] = c0[tid]; j1a[tid] = c1[tid]; }
}

// ---- bf16 copy of X + exact fp32 squared norms (one wave per row)
__global__ void prep_x(const float* __restrict__ X, unsigned short* __restrict__ Xb,
                       float* __restrict__ sqv) {
  int gw = (int)((blockIdx.x * blockDim.x + threadIdx.x) >> 6);
  int lane = threadIdx.x & 63;
  if (gw >= NPTS) return;
  const float* xr = X + (size_t)gw * DIM;
  float a = xr[lane], b = xr[lane + 64];
  Xb[(size_t)gw * DIM + lane] = f2bf(a);
  Xb[(size_t)gw * DIM + lane + 64] = f2bf(b);
  float s = a * a + b * b;
#pragma unroll
  for (int off = 32; off; off >>= 1) s += __shfl_xor(s, off);
  if (lane == 0) sqv[gw] = s;
}

// ---- two-sweep: (1) per-lane min2 -> per-row upper bound U on the 17th smallest,
//      (2) re-stream GEMM, append only d2 <= U, extract the 17 smallest -> scratch.
// Grid: 1024 blocks = 512 row-groups x 2 column-halves. Block = 4 waves; wave w
// scans columns [half*4096 + w*1024, +1024).
__global__ __launch_bounds__(256) void knn_main(
    const unsigned short* __restrict__ Xb, const float* __restrict__ sqv,
    const int* __restrict__ tgt, float* __restrict__ scr) {
  __shared__ float cand[16][128];      // min2 candidates for U extraction
  __shared__ float bufD[4][16][CAPW];
  __shared__ int   bufM[4][16][CAPW];
  __shared__ int   cnt[4][16];
  __shared__ float Uv[16];

  const int tid = threadIdx.x;
  const int w = tid >> 6;
  const int lane = tid & 63;
  const int quad = lane >> 4;
  const int l16 = lane & 15;
  const int rg = blockIdx.x >> 1;
  const int half = blockIdx.x & 1;
  const int rbase = rg * 16;
  const int colbase = half * 4096 + w * 1024;

  if (lane < 16) cnt[w][lane] = 0;

  // A fragments (16 rows x K=128), persistent. 16x16x32 bf16: A[m=lane&15][k=quad*8+j]
  bf16x8 afrag[4];
  {
    const unsigned short* arow = Xb + (size_t)(rbase + l16) * DIM;
#pragma unroll
    for (int kb = 0; kb < 4; kb++)
      afrag[kb] = *(const bf16x8*)(arow + kb * 32 + quad * 8);
  }
  float sqi[4]; int ti[4];
#pragma unroll
  for (int r = 0; r < 4; r++) { int rr = rbase + quad * 4 + r; sqi[r] = sqv[rr]; ti[r] = tgt[rr]; }

  // ---- sweep 1: per-lane two smallest d2 per row (registers only)
  float m1[4], m2[4];
#pragma unroll
  for (int r = 0; r < 4; r++) { m1[r] = BIG; m2[r] = BIG; }

  for (int t = 0; t < 64; t++) {
    const int col = colbase + t * 16 + l16;
    const unsigned short* brow = Xb + (size_t)col * DIM;
    bf16x8 bfrag[4];
#pragma unroll
    for (int kb = 0; kb < 4; kb++) bfrag[kb] = *(const bf16x8*)(brow + kb * 32 + quad * 8);
    f32x4 acc = {0.f, 0.f, 0.f, 0.f};
#pragma unroll
    for (int kb = 0; kb < 4; kb++)
      acc = __builtin_amdgcn_mfma_f32_16x16x32_bf16(afrag[kb], bfrag[kb], acc, 0, 0, 0);
    const float sqj = sqv[col];
#pragma unroll
    for (int r = 0; r < 4; r++) {
      float d2 = fmaf(-2.0f, acc[r], sqi[r] + sqj);
      d2 = (col == rbase + quad * 4 + r) ? BIG : d2;   // exclude diagonal
      m2[r] = fminf(m2[r], fmaxf(m1[r], d2));
      m1[r] = fminf(m1[r], d2);
    }
  }
  // publish min2 candidates: per row, 4 waves x 16 lanes x 2 = 128 real elements
#pragma unroll
  for (int r = 0; r < 4; r++) {
    int row = quad * 4 + r;
    cand[row][w * 32 + l16 * 2] = m1[r];
    cand[row][w * 32 + l16 * 2 + 1] = m2[r];
  }
  __syncthreads();

  // U[row] = 17th smallest of the 128-candidate subset (>= true row t17)
  for (int ri = 0; ri < 4; ri++) {
    int row = w * 4 + ri;
    float a = cand[row][lane], b = cand[row][64 + lane];
    float v17 = BIG;
    for (int round = 0; round < KSEL; round++) {
      float v = a; int idx = lane;
      if (b < v) { v = b; idx = lane | 64; }
#pragma unroll
      for (int off = 32; off; off >>= 1) {
        float ov = __shfl_xor(v, off);
        int   oi = __shfl_xor(idx, off);
        if (ov < v || (ov == v && oi < idx)) { v = ov; idx = oi; }
      }
      if ((idx & 63) == lane) { if (idx & 64) b = BIG; else a = BIG; }
      v17 = v;
    }
    if (lane == 0) Uv[row] = v17;
  }
  __syncthreads();
  float Ur[4];
#pragma unroll
  for (int r = 0; r < 4; r++) Ur[r] = Uv[quad * 4 + r];

  // ---- sweep 2: append d2 <= U (non-strict, so U==t17 keeps the threshold element)
  for (int t = 0; t < 64; t++) {
    const int col = colbase + t * 16 + l16;
    const unsigned short* brow = Xb + (size_t)col * DIM;
    bf16x8 bfrag[4];
#pragma unroll
    for (int kb = 0; kb < 4; kb++) bfrag[kb] = *(const bf16x8*)(brow + kb * 32 + quad * 8);
    f32x4 acc = {0.f, 0.f, 0.f, 0.f};
#pragma unroll
    for (int kb = 0; kb < 4; kb++)
      acc = __builtin_amdgcn_mfma_f32_16x16x32_bf16(afrag[kb], bfrag[kb], acc, 0, 0, 0);
    const float sqj = sqv[col];
    const int tj = tgt[col];
    bool p[4]; float dv[4];
#pragma unroll
    for (int r = 0; r < 4; r++) {
      float d2 = fmaf(-2.0f, acc[r], sqi[r] + sqj);
      d2 = (col == rbase + quad * 4 + r) ? BIG : d2;
      dv[r] = d2;
      p[r] = (d2 <= Ur[r]);
    }
    if (__any(p[0] | p[1] | p[2] | p[3])) {
#pragma unroll
      for (int r = 0; r < 4; r++) {
        if (p[r]) {
          int rl = quad * 4 + r;
          int pos = atomicAdd(&cnt[w][rl], 1);
          if (pos < CAPW) { bufD[w][rl][pos] = dv[r]; bufM[w][rl][pos] = (tj == ti[r]); }
        }
      }
    }
  }
  __syncthreads();

  // ---- finalize: per row, 17 smallest across the 4 wave buffers -> global scratch
  for (int ri = 0; ri < 4; ri++) {
    const int rl = w * 4 + ri;
    const int grow = rbase + rl;
    float e[4]; int m[4];
#pragma unroll
    for (int ww = 0; ww < 4; ww++) {
      int n = min(cnt[ww][rl], CAPW);
      if (lane < n) { e[ww] = bufD[ww][rl][lane]; m[ww] = bufM[ww][rl][lane]; }
      else { e[ww] = BIG; m[ww] = 0; }
    }
    float* srow = scr + (size_t)grow * (2 * KSEL) + half * KSEL;
    for (int round = 0; round < KSEL; round++) {
      float v = e[0]; int idx = lane;
      if (e[1] < v) { v = e[1]; idx = lane | (1 << 6); }
      if (e[2] < v) { v = e[2]; idx = lane | (2 << 6); }
      if (e[3] < v) { v = e[3]; idx = lane | (3 << 6); }
#pragma unroll
      for (int off = 32; off; off >>= 1) {
        float ov = __shfl_xor(v, off);
        int   oi = __shfl_xor(idx, off);
        if (ov < v || (ov == v && oi < idx)) { v = ov; idx = oi; }
      }
      if ((idx & 63) == lane) {
        int s = idx >> 6;
        unsigned ub = __float_as_uint(fmaxf(e[s], 0.0f));   // mask in sign bit
        if (m[s]) ub |= 0x80000000u;
        srow[round] = __uint_as_float(ub);
        e[s] = BIG;
      }
    }
  }
}

// ---- per-row merge of the two half-lists (34 candidates) + loss epilogue
__global__ __launch_bounds__(256) void knn_merge(
    const float* __restrict__ scr, const float* __restrict__ sqv,
    const int* __restrict__ tgt, const int* __restrict__ ccount,
    const int* __restrict__ j0a, const int* __restrict__ j1a,
    const float* __restrict__ X32, float* __restrict__ out) {
  __shared__ float blockAcc[4];
  const int tid = threadIdx.x;
  const int w = tid >> 6;
  const int lane = tid & 63;
  if (tid < 4) blockAcc[tid] = 0.0f;
  __syncthreads();
  for (int ri = 0; ri < 4; ri++) {
    const int grow = blockIdx.x * 16 + w * 4 + ri;
    float enc = (lane < 2 * KSEL) ? scr[(size_t)grow * (2 * KSEL) + lane] : BIG;
    unsigned ub = __float_as_uint(enc);
    int mfl = (lane < 2 * KSEL) ? (int)(ub >> 31) : 0;
    float e = __uint_as_float(ub & 0x7fffffffu);
    // exact 17th smallest of the union
    float work = e; float t17 = BIG;
    for (int round = 0; round < KSEL; round++) {
      float v = work; int idx = lane;
#pragma unroll
      for (int off = 32; off; off >>= 1) {
        float ov = __shfl_xor(v, off);
        int   oi = __shfl_xor(idx, off);
        if (ov < v || (ov == v && oi < idx)) { v = ov; idx = oi; }
      }
      if (idx == lane) work = BIG;
      t17 = v;
    }
    bool sel = (lane < 2 * KSEL) && (e < t17);   // strict, matches reference
    float ex = sel ? expf(-sqrtf(fmaxf(e, 1e-12f))) : 0.0f;
    float pls = (sel && mfl) ? ex : 0.0f;
    float nls = (sel && !mfl) ? ex : 0.0f;
    int cp = (sel && mfl) ? 1 : 0;
    int cn = (sel && !mfl) ? 1 : 0;
#pragma unroll
    for (int off = 32; off; off >>= 1) {
      pls += __shfl_xor(pls, off); nls += __shfl_xor(nls, off);
      cp  += __shfl_xor(cp, off);  cn  += __shfl_xor(cn, off);
    }
    const int c = tgt[grow];
    const int ncl = ccount[c];
    const bool valid = (ncl > 1) && (ncl < NPTS);
    if (valid) {
      float pos_eff;
      if (cp == 0) {
        const int jf = (grow == j0a[c]) ? j1a[c] : j0a[c];
        const float* xi = X32 + (size_t)grow * DIM;
        const float* xj = X32 + (size_t)jf * DIM;
        float pp = xi[lane] * xj[lane] + xi[lane + 64] * xj[lane + 64];
#pragma unroll
        for (int off = 32; off; off >>= 1) pp += __shfl_xor(pp, off);
        const float fb2 = sqv[grow] + sqv[jf] - 2.0f * pp;
        pos_eff = expf(-sqrtf(fmaxf(fb2, 1e-12f)));
      } else {
        pos_eff = pls;
      }
      if (lane == 0) {
        const float loss_i = -logf(pos_eff / (pos_eff + nls));
        const int cpa = (cp == 0) ? 1 : cp;
        atomicAdd(&blockAcc[0], loss_i);
        atomicAdd(&blockAcc[1], (cpa > cn) ? 1.0f : 0.0f);
        atomicAdd(&blockAcc[2], (float)cp);
        atomicAdd(&blockAcc[3], (float)cn);
      }
    }
  }
  __syncthreads();
  if (tid < 4) atomicAdd(&out[tid], blockAcc[tid] * (1.0f / (float)NPTS));
}

extern "C" void kernel_launch(void* const* d_in, const int* in_sizes, int n_in,
                              void* d_out, int out_size, void* d_ws, size_t ws_size,
                              hipStream_t stream) {
  const float* X = (const float*)d_in[0];
  const long long* targets = (const long long*)d_in[1];
  float* out = (float*)d_out;

  char* ws = (char*)d_ws;
  unsigned short* Xb = (unsigned short*)ws;                        // 2 MiB
  float* sqv  = (float*)(ws + (2u << 20));                         // 32 KiB
  int*   tgt  = (int*)  (ws + (2u << 20) + (32u << 10));           // 32 KiB
  int* ccount = (int*)  (ws + (2u << 20) + (64u << 10));           // 1.5 KiB
  int* j0a = ccount + NCLS;
  int* j1a = j0a + NCLS;
  float* scr = (float*)(ws + (2u << 20) + (128u << 10));           // 8192*34*4 = 1.06 MiB

  hipMemsetAsync(d_out, 0, 4 * sizeof(float), stream);
  prep_t<<<1, 256, 0, stream>>>(targets, tgt, ccount, j0a, j1a);
  prep_x<<<2048, 256, 0, stream>>>(X, Xb, sqv);
  knn_main<<<1024, 256, 0, stream>>>(Xb, sqv, tgt, scr);
  knn_merge<<<512, 256, 0, stream>>>(scr, sqv, tgt, ccount, j0a, j1a, X, out);
}